// Round 11
// baseline (686.933 us; speedup 1.0000x reference)
//
#include <hip/hip_runtime.h>

#define T_CTX 2048
#define C_DIM 1024
#define HQK   256
#define NVOC  50257

typedef float nfloat4 __attribute__((ext_vector_type(4)));

// ---------------------------------------------------------------------------
// Kernel 1 (single block, 1024 thr): builds first-occurrence map via an LDS
// hash table (atomicCAS claim + atomicMin pos) and emits the nonzero list
// for the expand scatter: (vlist[i], mlist[i]) = (token id, first position).
// ---------------------------------------------------------------------------
__global__ __launch_bounds__(1024) void k_build_first(const int* __restrict__ idx,
                                                      int* __restrict__ first,
                                                      int* __restrict__ nnz_g,
                                                      int* __restrict__ vlist,
                                                      int* __restrict__ mlist) {
    __shared__ int sidx[T_CTX];
    __shared__ int skey[4096];
    __shared__ int sval[4096];
    __shared__ int snnz;
    const int tid = threadIdx.x;
    for (int i = tid; i < T_CTX; i += 1024) sidx[i] = idx[i];
    for (int i = tid; i < 4096; i += 1024) { skey[i] = -1; sval[i] = 0x7fffffff; }
    if (tid == 0) snnz = 0;
    __syncthreads();
#pragma unroll
    for (int rep = 0; rep < 2; ++rep) {
        const int s = tid + rep * 1024;
        const int my = sidx[s];
        int h = (int)(((unsigned)my * 2654435761u) >> 16) & 4095;
        while (true) {
            int k = skey[h];
            if (k == my) break;
            if (k == -1) {
                int old = atomicCAS(&skey[h], -1, my);
                if (old == -1 || old == my) break;
            }
            h = (h + 1) & 4095;
        }
        atomicMin(&sval[h], s);
    }
    __syncthreads();
#pragma unroll
    for (int rep = 0; rep < 2; ++rep) {
        const int s = tid + rep * 1024;
        const int my = sidx[s];
        int h = (int)(((unsigned)my * 2654435761u) >> 16) & 4095;
        while (skey[h] != my) h = (h + 1) & 4095;
        const int mp = sval[h];
        first[s] = mp;
        if (mp == s) {
            int p = atomicAdd(&snnz, 1);
            vlist[p] = my; mlist[p] = s;
        }
    }
    __syncthreads();
    if (tid == 0) nnz_g[0] = snnz;
}

// ---------------------------------------------------------------------------
// Kernel 2: fused q/k projection.  64x64 tile, BK=32, 256 threads, 4x4 micro
// (2 B LDS / FMA) with global->register prefetch double-buffering.
// cols 0..255 -> qbuf [T][256]; cols 256..511 -> kT [256][T] (transposed).
// Grid (32,8) = 256 blocks = 1/CU.
// ---------------------------------------------------------------------------
__global__ __launch_bounds__(256) void k_gemm_qk(const float* __restrict__ x,
                                                 const float* __restrict__ Wq,
                                                 const float* __restrict__ Wk,
                                                 float* __restrict__ qbuf,
                                                 float* __restrict__ kT) {
    __shared__ __align__(16) float As[32 * 68];   // [kk][row] transposed
    __shared__ __align__(16) float Bs[32 * 68];   // [kk][col]
    const int row0 = blockIdx.x * 64;
    const int col0 = blockIdx.y * 64;
    const bool is_q = (col0 < HQK);
    const float* __restrict__ W = is_q ? Wq : Wk;
    const int wc0 = is_q ? col0 : (col0 - HQK);
    const int tid = threadIdx.x;
    const int tr = (tid >> 4) << 2;
    const int tc = (tid & 15) << 2;
    const int ar = tid >> 3, ak = (tid & 7) << 2;    // +32 rows for L=1
    const int bk = tid >> 4, bc = (tid & 15) << 2;   // +16 k for L=1
    float4 pa[2], pb[2];
#pragma unroll
    for (int L = 0; L < 2; ++L) {
        pa[L] = *reinterpret_cast<const float4*>(&x[(size_t)(row0 + ar + 32 * L) * C_DIM + ak]);
        pb[L] = *reinterpret_cast<const float4*>(&W[(size_t)(bk + 16 * L) * HQK + wc0 + bc]);
    }
    float acc[4][4] = {};
    for (int k0 = 0; k0 < C_DIM; k0 += 32) {
#pragma unroll
        for (int L = 0; L < 2; ++L) {
            const int arL = ar + 32 * L;
            As[(ak + 0) * 68 + arL] = pa[L].x; As[(ak + 1) * 68 + arL] = pa[L].y;
            As[(ak + 2) * 68 + arL] = pa[L].z; As[(ak + 3) * 68 + arL] = pa[L].w;
            *reinterpret_cast<float4*>(&Bs[(bk + 16 * L) * 68 + bc]) = pb[L];
        }
        __syncthreads();
        if (k0 + 32 < C_DIM) {
#pragma unroll
            for (int L = 0; L < 2; ++L) {
                pa[L] = *reinterpret_cast<const float4*>(&x[(size_t)(row0 + ar + 32 * L) * C_DIM + k0 + 32 + ak]);
                pb[L] = *reinterpret_cast<const float4*>(&W[(size_t)(k0 + 32 + bk + 16 * L) * HQK + wc0 + bc]);
            }
        }
#pragma unroll
        for (int kk = 0; kk < 32; ++kk) {
            float4 av = *reinterpret_cast<const float4*>(&As[kk * 68 + tr]);
            float4 bv = *reinterpret_cast<const float4*>(&Bs[kk * 68 + tc]);
            const float a[4] = {av.x, av.y, av.z, av.w};
            const float b[4] = {bv.x, bv.y, bv.z, bv.w};
#pragma unroll
            for (int i = 0; i < 4; ++i)
#pragma unroll
                for (int j = 0; j < 4; ++j) acc[i][j] = fmaf(a[i], b[j], acc[i][j]);
        }
        __syncthreads();
    }
    if (is_q) {
#pragma unroll
        for (int i = 0; i < 4; ++i) {
            float4 o = {acc[i][0], acc[i][1], acc[i][2], acc[i][3]};
            *reinterpret_cast<float4*>(&qbuf[(size_t)(row0 + tr + i) * HQK + col0 + tc]) = o;
        }
    } else {
#pragma unroll
        for (int j = 0; j < 4; ++j) {
            float4 o = {acc[0][j], acc[1][j], acc[2][j], acc[3][j]};
            *reinterpret_cast<float4*>(&kT[(size_t)(wc0 + tc + j) * T_CTX + row0 + tr]) = o;
        }
    }
}

// ---------------------------------------------------------------------------
// Kernel 3: causal score GEMM.  c[t][s] = q[t].k[s]/256 for causal tiles
// (diagonal-tile garbage above the diagonal is masked by the fold).
// 64x64 tile, BK=32, 256 threads, 4x4 micro + prefetch; K=256 -> 8 stages.
// Grid (32,32); upper-triangular blocks exit.  528 live blocks ~ 2/CU.
// ---------------------------------------------------------------------------
__global__ __launch_bounds__(256) void k_scores_gemm(const float* __restrict__ q,
                                                     const float* __restrict__ kT,
                                                     float* __restrict__ c) {
    const int bt = blockIdx.x, bs = blockIdx.y;
    if (bs > bt) return;
    __shared__ __align__(16) float As[32 * 68];
    __shared__ __align__(16) float Bs[32 * 68];
    const int row0 = bt * 64;   // t
    const int col0 = bs * 64;   // s
    const int tid = threadIdx.x;
    const int tr = (tid >> 4) << 2;
    const int tc = (tid & 15) << 2;
    const int ar = tid >> 3, ak = (tid & 7) << 2;
    const int bk = tid >> 4, bc = (tid & 15) << 2;
    float4 pa[2], pb[2];
#pragma unroll
    for (int L = 0; L < 2; ++L) {
        pa[L] = *reinterpret_cast<const float4*>(&q[(size_t)(row0 + ar + 32 * L) * HQK + ak]);
        pb[L] = *reinterpret_cast<const float4*>(&kT[(size_t)(bk + 16 * L) * T_CTX + col0 + bc]);
    }
    float acc[4][4] = {};
    for (int k0 = 0; k0 < HQK; k0 += 32) {
#pragma unroll
        for (int L = 0; L < 2; ++L) {
            const int arL = ar + 32 * L;
            As[(ak + 0) * 68 + arL] = pa[L].x; As[(ak + 1) * 68 + arL] = pa[L].y;
            As[(ak + 2) * 68 + arL] = pa[L].z; As[(ak + 3) * 68 + arL] = pa[L].w;
            *reinterpret_cast<float4*>(&Bs[(bk + 16 * L) * 68 + bc]) = pb[L];
        }
        __syncthreads();
        if (k0 + 32 < HQK) {
#pragma unroll
            for (int L = 0; L < 2; ++L) {
                pa[L] = *reinterpret_cast<const float4*>(&q[(size_t)(row0 + ar + 32 * L) * HQK + k0 + 32 + ak]);
                pb[L] = *reinterpret_cast<const float4*>(&kT[(size_t)(k0 + 32 + bk + 16 * L) * T_CTX + col0 + bc]);
            }
        }
#pragma unroll
        for (int kk = 0; kk < 32; ++kk) {
            float4 av = *reinterpret_cast<const float4*>(&As[kk * 68 + tr]);
            float4 bv = *reinterpret_cast<const float4*>(&Bs[kk * 68 + tc]);
            const float a[4] = {av.x, av.y, av.z, av.w};
            const float b[4] = {bv.x, bv.y, bv.z, bv.w};
#pragma unroll
            for (int i = 0; i < 4; ++i)
#pragma unroll
                for (int j = 0; j < 4; ++j) acc[i][j] = fmaf(a[i], b[j], acc[i][j]);
        }
        __syncthreads();
    }
    const float scale = 1.0f / 256.0f;
#pragma unroll
    for (int i = 0; i < 4; ++i) {
        float4 o = {acc[i][0] * scale, acc[i][1] * scale, acc[i][2] * scale, acc[i][3] * scale};
        *reinterpret_cast<float4*>(&c[(size_t)(row0 + tr + i) * T_CTX + col0 + tc]) = o;
    }
}

// ---------------------------------------------------------------------------
// Kernel 4 (fused fold+expand): block t
//   phase A: fold row t of c by first[] into LDS rowc[2048] (LDS atomics)
//   phase B: zero-stream out[t][:] with aligned nontemporal float4 stores,
//            then scatter the ~2006 nonzero entries: out[t][vlist[i]] =
//            rowc[mlist[i]] if mlist[i] <= t.
// (__syncthreads drains vmcnt -> zero stores are in L2 before the scatter;
//  vlist values are unique so scatter addresses never collide.)
// ---------------------------------------------------------------------------
__global__ __launch_bounds__(256) void k_fold_expand(const float* __restrict__ c,
                                                     const int* __restrict__ first,
                                                     const int* __restrict__ nnz_g,
                                                     const int* __restrict__ vlist,
                                                     const int* __restrict__ mlist,
                                                     float* __restrict__ out) {
    __shared__ float rowc[T_CTX];
    const int t = blockIdx.x;
    for (int i = threadIdx.x; i < T_CTX; i += 256) rowc[i] = 0.0f;
    __syncthreads();
    // fold: s in [0, t]
    const int nq = (t >> 2) + 1;
    for (int qd = threadIdx.x; qd < nq; qd += 256) {
        const int s0 = qd << 2;
        float4 v = *reinterpret_cast<const float4*>(&c[(size_t)t * T_CTX + s0]);
        int4 f4 = *reinterpret_cast<const int4*>(&first[s0]);
        if (s0 + 3 <= t) {
            atomicAdd(&rowc[f4.x], v.x); atomicAdd(&rowc[f4.y], v.y);
            atomicAdd(&rowc[f4.z], v.z); atomicAdd(&rowc[f4.w], v.w);
        } else {
            atomicAdd(&rowc[f4.x], v.x);
            if (s0 + 1 <= t) atomicAdd(&rowc[f4.y], v.y);
            if (s0 + 2 <= t) atomicAdd(&rowc[f4.z], v.z);
            if (s0 + 3 <= t) atomicAdd(&rowc[f4.w], v.w);
        }
    }
    // zero-stream the output row (no dependence on rowc -> before barrier)
    float* __restrict__ orow = out + (size_t)t * NVOC;
    const int lead = (4 - (t & 3)) & 3;   // (t*NVOC + lead) % 4 == 0
    if ((int)threadIdx.x < lead) orow[threadIdx.x] = 0.0f;
    const int nvec = (NVOC - lead) >> 2;
    const nfloat4 z4 = {0.0f, 0.0f, 0.0f, 0.0f};
    for (int i = threadIdx.x; i < nvec; i += 256)
        __builtin_nontemporal_store(z4, reinterpret_cast<nfloat4*>(&orow[lead + (i << 2)]));
    for (int v = lead + (nvec << 2) + threadIdx.x; v < NVOC; v += 256) orow[v] = 0.0f;
    __syncthreads();   // rowc complete AND zero stores drained (vmcnt(0))
    // scatter nonzeros
    const int nnz = nnz_g[0];
    for (int i = threadIdx.x; i < nnz; i += 256) {
        const int m = mlist[i];
        if (m <= t) orow[vlist[i]] = rowc[m];
    }
}

// ---------------------------------------------------------------------------
extern "C" void kernel_launch(void* const* d_in, const int* in_sizes, int n_in,
                              void* d_out, int out_size, void* d_ws, size_t ws_size,
                              hipStream_t stream) {
    const float* x   = (const float*)d_in[0];
    const int*   idx = (const int*)d_in[1];
    const float* Wq  = (const float*)d_in[2];
    const float* Wk  = (const float*)d_in[3];
    float* out = (float*)d_out;

    char* ws = (char*)d_ws;
    float* qbuf   = (float*)(ws);                               // 2 MB  [T][256]
    float* kT     = (float*)(ws + (2u << 20));                  // 2 MB  [256][T]
    float* c      = (float*)(ws + (4u << 20));                  // 16 MB [T][T]
    int*   first  = (int*)(ws + (20u << 20));                   // 8 KB
    int*   nnz_g  = (int*)(ws + (20u << 20) + (16u << 10));     // 4 B
    int*   vlist  = (int*)(ws + (20u << 20) + (17u << 10));     // 8 KB
    int*   mlist  = (int*)(ws + (20u << 20) + (26u << 10));     // 8 KB

    k_build_first<<<1, 1024, 0, stream>>>(idx, first, nnz_g, vlist, mlist);
    dim3 gg(32, 8);
    k_gemm_qk<<<gg, 256, 0, stream>>>(x, Wq, Wk, qbuf, kT);
    dim3 gs(32, 32);
    k_scores_gemm<<<gs, 256, 0, stream>>>(qbuf, kT, c);
    k_fold_expand<<<T_CTX, 256, 0, stream>>>(c, first, nnz_g, vlist, mlist, out);
}

// Round 12
// 537.196 us; speedup vs baseline: 1.2787x; 1.2787x over previous
//
#include <hip/hip_runtime.h>

#define T_CTX 2048
#define C_DIM 1024
#define HQK   256
#define NVOC  50257

typedef float nfloat4 __attribute__((ext_vector_type(4)));
typedef _Float16 h2 __attribute__((ext_vector_type(2)));
typedef _Float16 h4 __attribute__((ext_vector_type(4)));

#if defined(__has_builtin)
#if __has_builtin(__builtin_amdgcn_fdot2)
#define HAVE_FDOT2 1
#endif
#endif
__device__ __forceinline__ float fdot2acc(h2 a, h2 b, float c) {
#ifdef HAVE_FDOT2
    return __builtin_amdgcn_fdot2(a, b, c, false);
#else
    return c + (float)a.x * (float)b.x + (float)a.y * (float)b.y;
#endif
}

// ---------------------------------------------------------------------------
// Kernel 1 (single block, 1024 thr): clears vocab_map AND builds
// first-occurrence map via an LDS hash table (atomicCAS claim + atomicMin).
// (identical to R6 known-good)
// ---------------------------------------------------------------------------
__global__ __launch_bounds__(1024) void k_build_first(const int* __restrict__ idx,
                                                      int* __restrict__ first,
                                                      int* __restrict__ vocab_map) {
    __shared__ int sidx[T_CTX];
    __shared__ int skey[4096];
    __shared__ int sval[4096];
    const int tid = threadIdx.x;
    for (int i = tid; i < T_CTX; i += 1024) sidx[i] = idx[i];
    for (int i = tid; i < 4096; i += 1024) { skey[i] = -1; sval[i] = 0x7fffffff; }
    int4* vm4 = reinterpret_cast<int4*>(vocab_map);
    const int4 neg1 = make_int4(-1, -1, -1, -1);
    for (int i = tid; i < 12564; i += 1024) vm4[i] = neg1;
    if (tid == 0) vocab_map[NVOC - 1] = -1;
    __syncthreads();
#pragma unroll
    for (int rep = 0; rep < 2; ++rep) {
        const int s = tid + rep * 1024;
        const int my = sidx[s];
        int h = (int)(((unsigned)my * 2654435761u) >> 16) & 4095;
        while (true) {
            int k = skey[h];
            if (k == my) break;
            if (k == -1) {
                int old = atomicCAS(&skey[h], -1, my);
                if (old == -1 || old == my) break;
            }
            h = (h + 1) & 4095;
        }
        atomicMin(&sval[h], s);
    }
    __syncthreads();
#pragma unroll
    for (int rep = 0; rep < 2; ++rep) {
        const int s = tid + rep * 1024;
        const int my = sidx[s];
        int h = (int)(((unsigned)my * 2654435761u) >> 16) & 4095;
        while (skey[h] != my) h = (h + 1) & 4095;
        const int mp = sval[h];
        first[s] = mp;
        if (mp == s) vocab_map[my] = s;
    }
}

// ---------------------------------------------------------------------------
// Kernel 2: fused q/k projection (R6 geometry: 64x64 tile, BK=32, 512 thr,
// 2x4 micro, grid (32,8)=256 blocks) but with f16 LDS + v_dot2_f32_f16:
// halves LDS bytes/MAC and doubles MACs/instr.  fp32 accumulate.
// Outputs are f16: qbuf_h [T][256]; kTh [256][T] (transposed).
// ---------------------------------------------------------------------------
__global__ __launch_bounds__(512) void k_gemm_qk(const float* __restrict__ x,
                                                 const float* __restrict__ Wq,
                                                 const float* __restrict__ Wk,
                                                 _Float16* __restrict__ qbuf_h,
                                                 _Float16* __restrict__ kTh) {
    __shared__ h2 As2[16 * 68];          // [kk2][row]: k-pair per row
    __shared__ _Float16 BsH[16 * 136];   // [kk2][2*col + parity]
    const int row0 = blockIdx.x * 64;
    const int col0 = blockIdx.y * 64;
    const bool is_q = (col0 < HQK);
    const float* __restrict__ W = is_q ? Wq : Wk;
    const int wc0 = is_q ? col0 : (col0 - HQK);
    const int tid = threadIdx.x;
    const int tr = (tid >> 4) << 1;                  // 2 rows
    const int tc = (tid & 15) << 2;                  // 4 cols
    const int ar = tid >> 3, ak = (tid & 7) << 2;    // A: 64 rows x 8 k-quads
    const int bk = tid >> 4, bc = (tid & 15) << 2;   // B: 32 k x 16 col-quads
    float acc[2][4] = {};
    for (int k0 = 0; k0 < C_DIM; k0 += 32) {
        float4 a4 = *reinterpret_cast<const float4*>(&x[(size_t)(row0 + ar) * C_DIM + k0 + ak]);
        float4 b4 = *reinterpret_cast<const float4*>(&W[(size_t)(k0 + bk) * HQK + wc0 + bc]);
        As2[(ak >> 1) * 68 + ar]       = h2{(_Float16)a4.x, (_Float16)a4.y};
        As2[((ak >> 1) + 1) * 68 + ar] = h2{(_Float16)a4.z, (_Float16)a4.w};
        {
            const int r = (bk >> 1) * 136, p = bk & 1;
            BsH[r + ((bc + 0) << 1) + p] = (_Float16)b4.x;
            BsH[r + ((bc + 1) << 1) + p] = (_Float16)b4.y;
            BsH[r + ((bc + 2) << 1) + p] = (_Float16)b4.z;
            BsH[r + ((bc + 3) << 1) + p] = (_Float16)b4.w;
        }
        __syncthreads();
#pragma unroll
        for (int kk2 = 0; kk2 < 16; ++kk2) {
            h2 a0 = As2[kk2 * 68 + tr];
            h2 a1 = As2[kk2 * 68 + tr + 1];
            const h2* bp = reinterpret_cast<const h2*>(&BsH[kk2 * 136 + (tc << 1)]);
            h2 b0 = bp[0], b1 = bp[1], b2 = bp[2], b3 = bp[3];
            acc[0][0] = fdot2acc(a0, b0, acc[0][0]); acc[0][1] = fdot2acc(a0, b1, acc[0][1]);
            acc[0][2] = fdot2acc(a0, b2, acc[0][2]); acc[0][3] = fdot2acc(a0, b3, acc[0][3]);
            acc[1][0] = fdot2acc(a1, b0, acc[1][0]); acc[1][1] = fdot2acc(a1, b1, acc[1][1]);
            acc[1][2] = fdot2acc(a1, b2, acc[1][2]); acc[1][3] = fdot2acc(a1, b3, acc[1][3]);
        }
        __syncthreads();
    }
    if (is_q) {
#pragma unroll
        for (int i = 0; i < 2; ++i) {
            h4 o = {(_Float16)acc[i][0], (_Float16)acc[i][1], (_Float16)acc[i][2], (_Float16)acc[i][3]};
            *reinterpret_cast<h4*>(&qbuf_h[(size_t)(row0 + tr + i) * HQK + col0 + tc]) = o;
        }
    } else {
#pragma unroll
        for (int j = 0; j < 4; ++j) {
            h2 o = {(_Float16)acc[0][j], (_Float16)acc[1][j]};
            *reinterpret_cast<h2*>(&kTh[(size_t)(wc0 + tc + j) * T_CTX + row0 + tr]) = o;
        }
    }
}

// ---------------------------------------------------------------------------
// Kernel 3: causal score GEMM, f16 dot2 (same geometry as R6: 64x64, BK=32,
// 512 thr, 2x4 micro, grid (32,32), upper-tri exit).  c fp32.
// ---------------------------------------------------------------------------
__global__ __launch_bounds__(512) void k_scores_gemm(const _Float16* __restrict__ q,
                                                     const _Float16* __restrict__ kTh,
                                                     float* __restrict__ c) {
    const int bt = blockIdx.x, bs = blockIdx.y;
    if (bs > bt) return;
    __shared__ h2 As2[16 * 68];
    __shared__ _Float16 BsH[16 * 136];
    const int row0 = bt * 64;   // t
    const int col0 = bs * 64;   // s
    const int tid = threadIdx.x;
    const int tr = (tid >> 4) << 1;
    const int tc = (tid & 15) << 2;
    const int ar = tid >> 3, ak = (tid & 7) << 2;
    const int bk = tid >> 4, bc = (tid & 15) << 2;
    float acc[2][4] = {};
    for (int k0 = 0; k0 < HQK; k0 += 32) {
        h4 a4 = *reinterpret_cast<const h4*>(&q[(size_t)(row0 + ar) * HQK + k0 + ak]);
        h4 b4 = *reinterpret_cast<const h4*>(&kTh[(size_t)(k0 + bk) * T_CTX + col0 + bc]);
        As2[(ak >> 1) * 68 + ar]       = h2{a4.x, a4.y};
        As2[((ak >> 1) + 1) * 68 + ar] = h2{a4.z, a4.w};
        {
            const int r = (bk >> 1) * 136, p = bk & 1;
            BsH[r + ((bc + 0) << 1) + p] = b4.x;
            BsH[r + ((bc + 1) << 1) + p] = b4.y;
            BsH[r + ((bc + 2) << 1) + p] = b4.z;
            BsH[r + ((bc + 3) << 1) + p] = b4.w;
        }
        __syncthreads();
#pragma unroll
        for (int kk2 = 0; kk2 < 16; ++kk2) {
            h2 a0 = As2[kk2 * 68 + tr];
            h2 a1 = As2[kk2 * 68 + tr + 1];
            const h2* bp = reinterpret_cast<const h2*>(&BsH[kk2 * 136 + (tc << 1)]);
            h2 b0 = bp[0], b1 = bp[1], b2 = bp[2], b3 = bp[3];
            acc[0][0] = fdot2acc(a0, b0, acc[0][0]); acc[0][1] = fdot2acc(a0, b1, acc[0][1]);
            acc[0][2] = fdot2acc(a0, b2, acc[0][2]); acc[0][3] = fdot2acc(a0, b3, acc[0][3]);
            acc[1][0] = fdot2acc(a1, b0, acc[1][0]); acc[1][1] = fdot2acc(a1, b1, acc[1][1]);
            acc[1][2] = fdot2acc(a1, b2, acc[1][2]); acc[1][3] = fdot2acc(a1, b3, acc[1][3]);
        }
        __syncthreads();
    }
    const float scale = 1.0f / 256.0f;
#pragma unroll
    for (int i = 0; i < 2; ++i) {
        float4 o = {acc[i][0] * scale, acc[i][1] * scale, acc[i][2] * scale, acc[i][3] * scale};
        *reinterpret_cast<float4*>(&c[(size_t)(row0 + tr + i) * T_CTX + col0 + tc]) = o;
    }
}

// ---------------------------------------------------------------------------
// Kernel 4 (fused fold+expand) — identical to R6 known-good.
//   phase A: fold row t of c by first[] into LDS rowc[2048] (LDS atomics)
//   phase B: stream-expand rowc to out[t][:] via vocab_map gather with
//            aligned nontemporal float4 stores.
// ---------------------------------------------------------------------------
__global__ __launch_bounds__(256) void k_fold_expand(const float* __restrict__ c,
                                                     const int* __restrict__ first,
                                                     const int* __restrict__ vocab_map,
                                                     float* __restrict__ out) {
    __shared__ float rowc[T_CTX];
    const int t = blockIdx.x;
    for (int i = threadIdx.x; i < T_CTX; i += 256) rowc[i] = 0.0f;
    __syncthreads();
    const int nq = (t >> 2) + 1;
    for (int qd = threadIdx.x; qd < nq; qd += 256) {
        const int s0 = qd << 2;
        float4 v = *reinterpret_cast<const float4*>(&c[(size_t)t * T_CTX + s0]);
        int4 f4 = *reinterpret_cast<const int4*>(&first[s0]);
        if (s0 + 3 <= t) {
            atomicAdd(&rowc[f4.x], v.x); atomicAdd(&rowc[f4.y], v.y);
            atomicAdd(&rowc[f4.z], v.z); atomicAdd(&rowc[f4.w], v.w);
        } else {
            atomicAdd(&rowc[f4.x], v.x);
            if (s0 + 1 <= t) atomicAdd(&rowc[f4.y], v.y);
            if (s0 + 2 <= t) atomicAdd(&rowc[f4.z], v.z);
            if (s0 + 3 <= t) atomicAdd(&rowc[f4.w], v.w);
        }
    }
    __syncthreads();
    float* __restrict__ orow = out + (size_t)t * NVOC;
    const int lead = (4 - (t & 3)) & 3;
    if ((int)threadIdx.x < lead) {
        int m = vocab_map[threadIdx.x];
        orow[threadIdx.x] = (m >= 0) ? rowc[m] : 0.0f;
    }
    const int nvec = (NVOC - lead) >> 2;
    for (int i = threadIdx.x; i < nvec; i += 256) {
        const int v = lead + (i << 2);
        int m0 = vocab_map[v + 0], m1 = vocab_map[v + 1];
        int m2 = vocab_map[v + 2], m3 = vocab_map[v + 3];
        nfloat4 o;
        o.x = (m0 >= 0) ? rowc[m0] : 0.0f;
        o.y = (m1 >= 0) ? rowc[m1] : 0.0f;
        o.z = (m2 >= 0) ? rowc[m2] : 0.0f;
        o.w = (m3 >= 0) ? rowc[m3] : 0.0f;
        __builtin_nontemporal_store(o, reinterpret_cast<nfloat4*>(&orow[v]));
    }
    for (int v = lead + (nvec << 2) + threadIdx.x; v < NVOC; v += 256) {
        int m = vocab_map[v];
        orow[v] = (m >= 0) ? rowc[m] : 0.0f;
    }
}

// ---------------------------------------------------------------------------
extern "C" void kernel_launch(void* const* d_in, const int* in_sizes, int n_in,
                              void* d_out, int out_size, void* d_ws, size_t ws_size,
                              hipStream_t stream) {
    const float* x   = (const float*)d_in[0];
    const int*   idx = (const int*)d_in[1];
    const float* Wq  = (const float*)d_in[2];
    const float* Wk  = (const float*)d_in[3];
    float* out = (float*)d_out;

    char* ws = (char*)d_ws;
    _Float16* qbuf_h  = (_Float16*)(ws);                          // 1 MB  [T][256] f16
    _Float16* kTh     = (_Float16*)(ws + (1u << 20));             // 1 MB  [256][T] f16
    float*    c       = (float*)(ws + (2u << 20));                // 16 MB [T][T] fp32
    int*      first   = (int*)(ws + (18u << 20));                 // 8 KB
    int*      vocab_map = (int*)(ws + (18u << 20) + (16u << 10)); // ~200 KB

    k_build_first<<<1, 1024, 0, stream>>>(idx, first, vocab_map);
    dim3 gg(32, 8);
    k_gemm_qk<<<gg, 512, 0, stream>>>(x, Wq, Wk, qbuf_h, kTh);
    dim3 gs(32, 32);
    k_scores_gemm<<<gs, 512, 0, stream>>>(qbuf_h, kTh, c);
    k_fold_expand<<<T_CTX, 256, 0, stream>>>(c, first, vocab_map, out);
}

// Round 13
// 536.565 us; speedup vs baseline: 1.2802x; 1.0012x over previous
//
#include <hip/hip_runtime.h>

#define T_CTX 2048
#define C_DIM 1024
#define HQK   256
#define NVOC  50257
#define NBMW  394   // bitmap words: ceil((NVOC/4+1)/32)

typedef float nfloat4 __attribute__((ext_vector_type(4)));
typedef _Float16 h2 __attribute__((ext_vector_type(2)));
typedef _Float16 h4 __attribute__((ext_vector_type(4)));
typedef _Float16 h8 __attribute__((ext_vector_type(8)));
typedef float f32x4 __attribute__((ext_vector_type(4)));

#if defined(__has_builtin)
#if __has_builtin(__builtin_amdgcn_fdot2)
#define HAVE_FDOT2 1
#endif
#endif
__device__ __forceinline__ float fdot2acc(h2 a, h2 b, float c) {
#ifdef HAVE_FDOT2
    return __builtin_amdgcn_fdot2(a, b, c, false);
#else
    return c + (float)a.x * (float)b.x + (float)a.y * (float)b.y;
#endif
}

// ---------------------------------------------------------------------------
// Kernel 1 (single block, 1024 thr): clears vocab_map, builds first-occurrence
// map via LDS hash table, emits per-vocab-quad nonzero bitmap.
// ---------------------------------------------------------------------------
__global__ __launch_bounds__(1024) void k_build_first(const int* __restrict__ idx,
                                                      int* __restrict__ first,
                                                      int* __restrict__ vocab_map,
                                                      unsigned* __restrict__ bm) {
    __shared__ int sidx[T_CTX];
    __shared__ int skey[4096];
    __shared__ int sval[4096];
    __shared__ unsigned sbm[NBMW];
    const int tid = threadIdx.x;
    for (int i = tid; i < T_CTX; i += 1024) sidx[i] = idx[i];
    for (int i = tid; i < 4096; i += 1024) { skey[i] = -1; sval[i] = 0x7fffffff; }
    for (int i = tid; i < NBMW; i += 1024) sbm[i] = 0u;
    int4* vm4 = reinterpret_cast<int4*>(vocab_map);
    const int4 neg1 = make_int4(-1, -1, -1, -1);
    for (int i = tid; i < 12564; i += 1024) vm4[i] = neg1;
    if (tid == 0) vocab_map[NVOC - 1] = -1;
    __syncthreads();
#pragma unroll
    for (int rep = 0; rep < 2; ++rep) {
        const int s = tid + rep * 1024;
        const int my = sidx[s];
        int h = (int)(((unsigned)my * 2654435761u) >> 16) & 4095;
        while (true) {
            int k = skey[h];
            if (k == my) break;
            if (k == -1) {
                int old = atomicCAS(&skey[h], -1, my);
                if (old == -1 || old == my) break;
            }
            h = (h + 1) & 4095;
        }
        atomicMin(&sval[h], s);
    }
    __syncthreads();
#pragma unroll
    for (int rep = 0; rep < 2; ++rep) {
        const int s = tid + rep * 1024;
        const int my = sidx[s];
        int h = (int)(((unsigned)my * 2654435761u) >> 16) & 4095;
        while (skey[h] != my) h = (h + 1) & 4095;
        const int mp = sval[h];
        first[s] = mp;
        if (mp == s) {
            vocab_map[my] = s;
            const int qd = my >> 2;
            atomicOr(&sbm[qd >> 5], 1u << (qd & 31));
        }
    }
    __syncthreads();
    for (int i = tid; i < NBMW; i += 1024) bm[i] = sbm[i];
}

// ---------------------------------------------------------------------------
// Kernel 2: fused q/k projection (R12 fdot2 structure, 64x64/BK=32/512thr/2x4).
// BOTH outputs row-major f16 [T][256]: qbuf_h and kbuf_h (k no longer
// transposed -- the MFMA scores kernel wants row-major for both operands).
// ---------------------------------------------------------------------------
__global__ __launch_bounds__(512) void k_gemm_qk(const float* __restrict__ x,
                                                 const float* __restrict__ Wq,
                                                 const float* __restrict__ Wk,
                                                 _Float16* __restrict__ qbuf_h,
                                                 _Float16* __restrict__ kbuf_h) {
    __shared__ h2 As2[16 * 68];          // [kk2][row]
    __shared__ _Float16 BsH[16 * 136];   // [kk2][2*col + parity]
    const int row0 = blockIdx.x * 64;
    const int col0 = blockIdx.y * 64;
    const bool is_q = (col0 < HQK);
    const float* __restrict__ W = is_q ? Wq : Wk;
    _Float16* __restrict__ obuf = is_q ? qbuf_h : kbuf_h;
    const int wc0 = is_q ? col0 : (col0 - HQK);
    const int tid = threadIdx.x;
    const int tr = (tid >> 4) << 1;
    const int tc = (tid & 15) << 2;
    const int ar = tid >> 3, ak = (tid & 7) << 2;
    const int bk = tid >> 4, bc = (tid & 15) << 2;
    float acc[2][4] = {};
    for (int k0 = 0; k0 < C_DIM; k0 += 32) {
        float4 a4 = *reinterpret_cast<const float4*>(&x[(size_t)(row0 + ar) * C_DIM + k0 + ak]);
        float4 b4 = *reinterpret_cast<const float4*>(&W[(size_t)(k0 + bk) * HQK + wc0 + bc]);
        As2[(ak >> 1) * 68 + ar]       = h2{(_Float16)a4.x, (_Float16)a4.y};
        As2[((ak >> 1) + 1) * 68 + ar] = h2{(_Float16)a4.z, (_Float16)a4.w};
        {
            const int r = (bk >> 1) * 136, p = bk & 1;
            BsH[r + ((bc + 0) << 1) + p] = (_Float16)b4.x;
            BsH[r + ((bc + 1) << 1) + p] = (_Float16)b4.y;
            BsH[r + ((bc + 2) << 1) + p] = (_Float16)b4.z;
            BsH[r + ((bc + 3) << 1) + p] = (_Float16)b4.w;
        }
        __syncthreads();
#pragma unroll
        for (int kk2 = 0; kk2 < 16; ++kk2) {
            h2 a0 = As2[kk2 * 68 + tr];
            h2 a1 = As2[kk2 * 68 + tr + 1];
            const h2* bp = reinterpret_cast<const h2*>(&BsH[kk2 * 136 + (tc << 1)]);
            h2 b0 = bp[0], b1 = bp[1], b2 = bp[2], b3 = bp[3];
            acc[0][0] = fdot2acc(a0, b0, acc[0][0]); acc[0][1] = fdot2acc(a0, b1, acc[0][1]);
            acc[0][2] = fdot2acc(a0, b2, acc[0][2]); acc[0][3] = fdot2acc(a0, b3, acc[0][3]);
            acc[1][0] = fdot2acc(a1, b0, acc[1][0]); acc[1][1] = fdot2acc(a1, b1, acc[1][1]);
            acc[1][2] = fdot2acc(a1, b2, acc[1][2]); acc[1][3] = fdot2acc(a1, b3, acc[1][3]);
        }
        __syncthreads();
    }
#pragma unroll
    for (int i = 0; i < 2; ++i) {
        h4 o = {(_Float16)acc[i][0], (_Float16)acc[i][1], (_Float16)acc[i][2], (_Float16)acc[i][3]};
        *reinterpret_cast<h4*>(&obuf[(size_t)(row0 + tr + i) * HQK + wc0 + tc]) = o;
    }
}

// ---------------------------------------------------------------------------
// Kernel 3: causal score GEMM via MFMA f16 (LDS-free; q/kb are 1 MB each ->
// L2-resident; fragments load direct from global, 16 B contiguous per lane).
// Block = 4 waves; wave w owns rows row0+16w..+15, 4 col-tiles, K=256.
// A[r][k]=q[row0+16w+r][k]; B[k][c]=kb[col0+16ct+c][k];
// lane layout: A row=lane&15, k=(lane>>4)*8+j; B col=lane&15, same k.
// D: col=lane&15, row=(lane>>4)*4+reg (m89-verified).
// Diagonal-block upper-triangle garbage is masked by the fold.
// ---------------------------------------------------------------------------
__global__ __launch_bounds__(256) void k_scores_mfma(const _Float16* __restrict__ q,
                                                     const _Float16* __restrict__ kb,
                                                     float* __restrict__ c) {
    const int bt = blockIdx.x, bs = blockIdx.y;
    if (bs > bt) return;
    const int row0 = bt * 64, col0 = bs * 64;
    const int w = threadIdx.x >> 6;
    const int lane = threadIdx.x & 63;
    const int arow = row0 + 16 * w + (lane & 15);
    const int kgrp = (lane >> 4) << 3;
    f32x4 acc[4] = {};
#pragma unroll
    for (int k0 = 0; k0 < HQK; k0 += 32) {
        h8 a = *reinterpret_cast<const h8*>(&q[(size_t)arow * HQK + k0 + kgrp]);
#pragma unroll
        for (int ct = 0; ct < 4; ++ct) {
            h8 b = *reinterpret_cast<const h8*>(&kb[(size_t)(col0 + 16 * ct + (lane & 15)) * HQK + k0 + kgrp]);
            acc[ct] = __builtin_amdgcn_mfma_f32_16x16x32_f16(a, b, acc[ct], 0, 0, 0);
        }
    }
    const float scale = 1.0f / 256.0f;
    const int orow = row0 + 16 * w + ((lane >> 4) << 2);
    const int ocol = col0 + (lane & 15);
#pragma unroll
    for (int ct = 0; ct < 4; ++ct)
#pragma unroll
        for (int r = 0; r < 4; ++r)
            c[(size_t)(orow + r) * T_CTX + ocol + 16 * ct] = acc[ct][r] * scale;
}

// ---------------------------------------------------------------------------
// Kernel 4 (fused fold+expand): fold row t of c by first[] into LDS rowc,
// then stream out[t][:].  Bitmap fast-path: quads with no nonzero vocab
// entry store zeros without touching vocab_map (saves ~84% of gather loads).
// ---------------------------------------------------------------------------
__global__ __launch_bounds__(256) void k_fold_expand(const float* __restrict__ c,
                                                     const int* __restrict__ first,
                                                     const int* __restrict__ vocab_map,
                                                     const unsigned* __restrict__ bm,
                                                     float* __restrict__ out) {
    __shared__ float rowc[T_CTX];
    __shared__ unsigned sbm[NBMW];
    const int t = blockIdx.x;
    for (int i = threadIdx.x; i < T_CTX; i += 256) rowc[i] = 0.0f;
    for (int i = threadIdx.x; i < NBMW; i += 256) sbm[i] = bm[i];
    __syncthreads();
    const int nq = (t >> 2) + 1;
    for (int qd = threadIdx.x; qd < nq; qd += 256) {
        const int s0 = qd << 2;
        float4 v = *reinterpret_cast<const float4*>(&c[(size_t)t * T_CTX + s0]);
        int4 f4 = *reinterpret_cast<const int4*>(&first[s0]);
        if (s0 + 3 <= t) {
            atomicAdd(&rowc[f4.x], v.x); atomicAdd(&rowc[f4.y], v.y);
            atomicAdd(&rowc[f4.z], v.z); atomicAdd(&rowc[f4.w], v.w);
        } else {
            atomicAdd(&rowc[f4.x], v.x);
            if (s0 + 1 <= t) atomicAdd(&rowc[f4.y], v.y);
            if (s0 + 2 <= t) atomicAdd(&rowc[f4.z], v.z);
            if (s0 + 3 <= t) atomicAdd(&rowc[f4.w], v.w);
        }
    }
    __syncthreads();
    float* __restrict__ orow = out + (size_t)t * NVOC;
    const int lead = (4 - (t & 3)) & 3;
    if ((int)threadIdx.x < lead) {
        int m = vocab_map[threadIdx.x];
        orow[threadIdx.x] = (m >= 0) ? rowc[m] : 0.0f;
    }
    const int nvec = (NVOC - lead) >> 2;
    const nfloat4 z4 = {0.0f, 0.0f, 0.0f, 0.0f};
    for (int i = threadIdx.x; i < nvec; i += 256) {
        const int v = lead + (i << 2);
        const int q0 = v >> 2, q1 = (v + 3) >> 2;
        const unsigned hit = ((sbm[q0 >> 5] >> (q0 & 31)) | (sbm[q1 >> 5] >> (q1 & 31))) & 1u;
        if (hit) {
            int m0 = vocab_map[v + 0], m1 = vocab_map[v + 1];
            int m2 = vocab_map[v + 2], m3 = vocab_map[v + 3];
            nfloat4 o;
            o.x = (m0 >= 0) ? rowc[m0] : 0.0f;
            o.y = (m1 >= 0) ? rowc[m1] : 0.0f;
            o.z = (m2 >= 0) ? rowc[m2] : 0.0f;
            o.w = (m3 >= 0) ? rowc[m3] : 0.0f;
            __builtin_nontemporal_store(o, reinterpret_cast<nfloat4*>(&orow[v]));
        } else {
            __builtin_nontemporal_store(z4, reinterpret_cast<nfloat4*>(&orow[v]));
        }
    }
    for (int v = lead + (nvec << 2) + threadIdx.x; v < NVOC; v += 256) {
        int m = vocab_map[v];
        orow[v] = (m >= 0) ? rowc[m] : 0.0f;
    }
}

// ---------------------------------------------------------------------------
extern "C" void kernel_launch(void* const* d_in, const int* in_sizes, int n_in,
                              void* d_out, int out_size, void* d_ws, size_t ws_size,
                              hipStream_t stream) {
    const float* x   = (const float*)d_in[0];
    const int*   idx = (const int*)d_in[1];
    const float* Wq  = (const float*)d_in[2];
    const float* Wk  = (const float*)d_in[3];
    float* out = (float*)d_out;

    char* ws = (char*)d_ws;
    _Float16* qbuf_h   = (_Float16*)(ws);                          // 1 MB  [T][256] f16
    _Float16* kbuf_h   = (_Float16*)(ws + (1u << 20));             // 1 MB  [T][256] f16
    float*    c        = (float*)(ws + (2u << 20));                // 16 MB [T][T] fp32
    int*      first    = (int*)(ws + (18u << 20));                 // 8 KB
    int*      vocab_map = (int*)(ws + (18u << 20) + (16u << 10));  // ~200 KB
    unsigned* bm       = (unsigned*)(ws + (19u << 20));            // 1.6 KB

    k_build_first<<<1, 1024, 0, stream>>>(idx, first, vocab_map, bm);
    dim3 gg(32, 8);
    k_gemm_qk<<<gg, 512, 0, stream>>>(x, Wq, Wk, qbuf_h, kbuf_h);
    dim3 gs(32, 32);
    k_scores_mfma<<<gs, 256, 0, stream>>>(qbuf_h, kbuf_h, c);
    k_fold_expand<<<T_CTX, 256, 0, stream>>>(c, first, vocab_map, bm, out);
}

// Round 14
// 525.869 us; speedup vs baseline: 1.3063x; 1.0203x over previous
//
#include <hip/hip_runtime.h>

#define T_CTX 2048
#define C_DIM 1024
#define HQK   256
#define NVOC  50257
#define NBMW  394   // bitmap words: ceil((NVOC/4+1)/32)

typedef float nfloat4 __attribute__((ext_vector_type(4)));
typedef _Float16 h2 __attribute__((ext_vector_type(2)));
typedef _Float16 h4 __attribute__((ext_vector_type(4)));
typedef _Float16 h8 __attribute__((ext_vector_type(8)));
typedef float f32x4 __attribute__((ext_vector_type(4)));

#if defined(__has_builtin)
#if __has_builtin(__builtin_amdgcn_fdot2)
#define HAVE_FDOT2 1
#endif
#endif
__device__ __forceinline__ float fdot2acc(h2 a, h2 b, float c) {
#ifdef HAVE_FDOT2
    return __builtin_amdgcn_fdot2(a, b, c, false);
#else
    return c + (float)a.x * (float)b.x + (float)a.y * (float)b.y;
#endif
}

// ---------------------------------------------------------------------------
// Kernel 1 (merged): grid 257 x 512 thr.
//  blocks 0..255 : fused q/k projection (R12 structure: 64x64 tile, BK=32,
//                  2x4 micro, f16 LDS + v_dot2_f32_f16, fp32 accum).
//                  Outputs row-major f16: qbuf_h [T][256], kbuf_h [T][256].
//  block 256     : first-occurrence build (LDS hash table) + vocab_map clear
//                  + nonzero-quad bitmap.  Runs concurrently on its own CU.
// Shared LDS is a union of the two layouts (42.6 KB).
// ---------------------------------------------------------------------------
__global__ __launch_bounds__(512) void k_proj_build(const float* __restrict__ x,
                                                    const float* __restrict__ Wq,
                                                    const float* __restrict__ Wk,
                                                    const int* __restrict__ idx,
                                                    _Float16* __restrict__ qbuf_h,
                                                    _Float16* __restrict__ kbuf_h,
                                                    int* __restrict__ first,
                                                    int* __restrict__ vocab_map,
                                                    unsigned* __restrict__ bm) {
    __shared__ __align__(16) int smem_i[10640];
    const int tid = threadIdx.x;

    if (blockIdx.x == 256) {
        // ---- build_first body (512 threads) ----
        int* sidx = smem_i;                       // 2048
        int* skey = smem_i + 2048;                // 4096
        int* sval = smem_i + 6144;                // 4096
        unsigned* sbm = (unsigned*)(smem_i + 10240);  // 394
        for (int i = tid; i < T_CTX; i += 512) sidx[i] = idx[i];
        for (int i = tid; i < 4096; i += 512) { skey[i] = -1; sval[i] = 0x7fffffff; }
        for (int i = tid; i < NBMW; i += 512) sbm[i] = 0u;
        int4* vm4 = reinterpret_cast<int4*>(vocab_map);
        const int4 neg1 = make_int4(-1, -1, -1, -1);
        for (int i = tid; i < 12564; i += 512) vm4[i] = neg1;
        if (tid == 0) vocab_map[NVOC - 1] = -1;
        __syncthreads();
        for (int s = tid; s < T_CTX; s += 512) {
            const int my = sidx[s];
            int h = (int)(((unsigned)my * 2654435761u) >> 16) & 4095;
            while (true) {
                int k = skey[h];
                if (k == my) break;
                if (k == -1) {
                    int old = atomicCAS(&skey[h], -1, my);
                    if (old == -1 || old == my) break;
                }
                h = (h + 1) & 4095;
            }
            atomicMin(&sval[h], s);
        }
        __syncthreads();
        for (int s = tid; s < T_CTX; s += 512) {
            const int my = sidx[s];
            int h = (int)(((unsigned)my * 2654435761u) >> 16) & 4095;
            while (skey[h] != my) h = (h + 1) & 4095;
            const int mp = sval[h];
            first[s] = mp;
            if (mp == s) {
                vocab_map[my] = s;
                const int qd = my >> 2;
                atomicOr(&sbm[qd >> 5], 1u << (qd & 31));
            }
        }
        __syncthreads();
        for (int i = tid; i < NBMW; i += 512) bm[i] = sbm[i];
        return;
    }

    // ---- projection GEMM body (R12 structure) ----
    h2* As2 = reinterpret_cast<h2*>(smem_i);                    // 16*68 h2
    _Float16* BsH = reinterpret_cast<_Float16*>(smem_i + 1088); // 16*136 f16
    const int row0 = (blockIdx.x >> 3) * 64;
    const int col0 = (blockIdx.x & 7) * 64;
    const bool is_q = (col0 < HQK);
    const float* __restrict__ W = is_q ? Wq : Wk;
    _Float16* __restrict__ obuf = is_q ? qbuf_h : kbuf_h;
    const int wc0 = is_q ? col0 : (col0 - HQK);
    const int tr = (tid >> 4) << 1;
    const int tc = (tid & 15) << 2;
    const int ar = tid >> 3, ak = (tid & 7) << 2;
    const int bk = tid >> 4, bc = (tid & 15) << 2;
    float acc[2][4] = {};
    for (int k0 = 0; k0 < C_DIM; k0 += 32) {
        float4 a4 = *reinterpret_cast<const float4*>(&x[(size_t)(row0 + ar) * C_DIM + k0 + ak]);
        float4 b4 = *reinterpret_cast<const float4*>(&W[(size_t)(k0 + bk) * HQK + wc0 + bc]);
        As2[(ak >> 1) * 68 + ar]       = h2{(_Float16)a4.x, (_Float16)a4.y};
        As2[((ak >> 1) + 1) * 68 + ar] = h2{(_Float16)a4.z, (_Float16)a4.w};
        {
            const int r = (bk >> 1) * 136, p = bk & 1;
            BsH[r + ((bc + 0) << 1) + p] = (_Float16)b4.x;
            BsH[r + ((bc + 1) << 1) + p] = (_Float16)b4.y;
            BsH[r + ((bc + 2) << 1) + p] = (_Float16)b4.z;
            BsH[r + ((bc + 3) << 1) + p] = (_Float16)b4.w;
        }
        __syncthreads();
#pragma unroll
        for (int kk2 = 0; kk2 < 16; ++kk2) {
            h2 a0 = As2[kk2 * 68 + tr];
            h2 a1 = As2[kk2 * 68 + tr + 1];
            const h2* bp = reinterpret_cast<const h2*>(&BsH[kk2 * 136 + (tc << 1)]);
            h2 b0 = bp[0], b1 = bp[1], b2 = bp[2], b3 = bp[3];
            acc[0][0] = fdot2acc(a0, b0, acc[0][0]); acc[0][1] = fdot2acc(a0, b1, acc[0][1]);
            acc[0][2] = fdot2acc(a0, b2, acc[0][2]); acc[0][3] = fdot2acc(a0, b3, acc[0][3]);
            acc[1][0] = fdot2acc(a1, b0, acc[1][0]); acc[1][1] = fdot2acc(a1, b1, acc[1][1]);
            acc[1][2] = fdot2acc(a1, b2, acc[1][2]); acc[1][3] = fdot2acc(a1, b3, acc[1][3]);
        }
        __syncthreads();
    }
#pragma unroll
    for (int i = 0; i < 2; ++i) {
        h4 o = {(_Float16)acc[i][0], (_Float16)acc[i][1], (_Float16)acc[i][2], (_Float16)acc[i][3]};
        *reinterpret_cast<h4*>(&obuf[(size_t)(row0 + tr + i) * HQK + wc0 + tc]) = o;
    }
}

// ---------------------------------------------------------------------------
// Kernel 2: causal score GEMM via MFMA f16 (LDS-free; q/kb L2-resident).
// c stored as f16 (scaled), halving scores->fold L2 traffic.
// D layout: col=lane&15, row=(lane>>4)*4+reg (m89-verified, R13-validated).
// ---------------------------------------------------------------------------
__global__ __launch_bounds__(256) void k_scores_mfma(const _Float16* __restrict__ q,
                                                     const _Float16* __restrict__ kb,
                                                     _Float16* __restrict__ c) {
    const int bt = blockIdx.x, bs = blockIdx.y;
    if (bs > bt) return;
    const int row0 = bt * 64, col0 = bs * 64;
    const int w = threadIdx.x >> 6;
    const int lane = threadIdx.x & 63;
    const int arow = row0 + 16 * w + (lane & 15);
    const int kgrp = (lane >> 4) << 3;
    f32x4 acc[4] = {};
#pragma unroll
    for (int k0 = 0; k0 < HQK; k0 += 32) {
        h8 a = *reinterpret_cast<const h8*>(&q[(size_t)arow * HQK + k0 + kgrp]);
#pragma unroll
        for (int ct = 0; ct < 4; ++ct) {
            h8 b = *reinterpret_cast<const h8*>(&kb[(size_t)(col0 + 16 * ct + (lane & 15)) * HQK + k0 + kgrp]);
            acc[ct] = __builtin_amdgcn_mfma_f32_16x16x32_f16(a, b, acc[ct], 0, 0, 0);
        }
    }
    const float scale = 1.0f / 256.0f;
    const int orow = row0 + 16 * w + ((lane >> 4) << 2);
    const int ocol = col0 + (lane & 15);
#pragma unroll
    for (int ct = 0; ct < 4; ++ct)
#pragma unroll
        for (int r = 0; r < 4; ++r)
            c[(size_t)(orow + r) * T_CTX + ocol + 16 * ct] = (_Float16)(acc[ct][r] * scale);
}

// ---------------------------------------------------------------------------
// Kernel 3 (fused fold+expand): fold row t of c (f16) by first[] into LDS
// rowc (fp32 LDS atomics), then stream out[t][:] with the bitmap fast-path
// (quads with no nonzero vocab entry store zeros without gather loads).
// ---------------------------------------------------------------------------
__global__ __launch_bounds__(256) void k_fold_expand(const _Float16* __restrict__ c,
                                                     const int* __restrict__ first,
                                                     const int* __restrict__ vocab_map,
                                                     const unsigned* __restrict__ bm,
                                                     float* __restrict__ out) {
    __shared__ float rowc[T_CTX];
    __shared__ unsigned sbm[NBMW];
    const int t = blockIdx.x;
    for (int i = threadIdx.x; i < T_CTX; i += 256) rowc[i] = 0.0f;
    for (int i = threadIdx.x; i < NBMW; i += 256) sbm[i] = bm[i];
    __syncthreads();
    const int nq = (t >> 2) + 1;
    for (int qd = threadIdx.x; qd < nq; qd += 256) {
        const int s0 = qd << 2;
        h4 v = *reinterpret_cast<const h4*>(&c[(size_t)t * T_CTX + s0]);
        int4 f4 = *reinterpret_cast<const int4*>(&first[s0]);
        if (s0 + 3 <= t) {
            atomicAdd(&rowc[f4.x], (float)v.x); atomicAdd(&rowc[f4.y], (float)v.y);
            atomicAdd(&rowc[f4.z], (float)v.z); atomicAdd(&rowc[f4.w], (float)v.w);
        } else {
            atomicAdd(&rowc[f4.x], (float)v.x);
            if (s0 + 1 <= t) atomicAdd(&rowc[f4.y], (float)v.y);
            if (s0 + 2 <= t) atomicAdd(&rowc[f4.z], (float)v.z);
            if (s0 + 3 <= t) atomicAdd(&rowc[f4.w], (float)v.w);
        }
    }
    __syncthreads();
    float* __restrict__ orow = out + (size_t)t * NVOC;
    const int lead = (4 - (t & 3)) & 3;
    if ((int)threadIdx.x < lead) {
        int m = vocab_map[threadIdx.x];
        orow[threadIdx.x] = (m >= 0) ? rowc[m] : 0.0f;
    }
    const int nvec = (NVOC - lead) >> 2;
    const nfloat4 z4 = {0.0f, 0.0f, 0.0f, 0.0f};
    for (int i = threadIdx.x; i < nvec; i += 256) {
        const int v = lead + (i << 2);
        const int q0 = v >> 2, q1 = (v + 3) >> 2;
        const unsigned hit = ((sbm[q0 >> 5] >> (q0 & 31)) | (sbm[q1 >> 5] >> (q1 & 31))) & 1u;
        if (hit) {
            int m0 = vocab_map[v + 0], m1 = vocab_map[v + 1];
            int m2 = vocab_map[v + 2], m3 = vocab_map[v + 3];
            nfloat4 o;
            o.x = (m0 >= 0) ? rowc[m0] : 0.0f;
            o.y = (m1 >= 0) ? rowc[m1] : 0.0f;
            o.z = (m2 >= 0) ? rowc[m2] : 0.0f;
            o.w = (m3 >= 0) ? rowc[m3] : 0.0f;
            __builtin_nontemporal_store(o, reinterpret_cast<nfloat4*>(&orow[v]));
        } else {
            __builtin_nontemporal_store(z4, reinterpret_cast<nfloat4*>(&orow[v]));
        }
    }
    for (int v = lead + (nvec << 2) + threadIdx.x; v < NVOC; v += 256) {
        int m = vocab_map[v];
        orow[v] = (m >= 0) ? rowc[m] : 0.0f;
    }
}

// ---------------------------------------------------------------------------
extern "C" void kernel_launch(void* const* d_in, const int* in_sizes, int n_in,
                              void* d_out, int out_size, void* d_ws, size_t ws_size,
                              hipStream_t stream) {
    const float* x   = (const float*)d_in[0];
    const int*   idx = (const int*)d_in[1];
    const float* Wq  = (const float*)d_in[2];
    const float* Wk  = (const float*)d_in[3];
    float* out = (float*)d_out;

    char* ws = (char*)d_ws;
    _Float16* qbuf_h   = (_Float16*)(ws);                          // 1 MB  [T][256] f16
    _Float16* kbuf_h   = (_Float16*)(ws + (1u << 20));             // 1 MB  [T][256] f16
    _Float16* c        = (_Float16*)(ws + (2u << 20));             // 8 MB  [T][T] f16
    int*      first    = (int*)(ws + (10u << 20));                 // 8 KB
    int*      vocab_map = (int*)(ws + (10u << 20) + (16u << 10));  // ~200 KB
    unsigned* bm       = (unsigned*)(ws + (11u << 20));            // 1.6 KB

    k_proj_build<<<257, 512, 0, stream>>>(x, Wq, Wk, idx, qbuf_h, kbuf_h,
                                          first, vocab_map, bm);
    dim3 gs(32, 32);
    k_scores_mfma<<<gs, 256, 0, stream>>>(qbuf_h, kbuf_h, c);
    k_fold_expand<<<T_CTX, 256, 0, stream>>>(c, first, vocab_map, bm, out);
}